// Round 1
// baseline (5859.066 us; speedup 1.0000x reference)
//
#include <hip/hip_runtime.h>

#define NN   100000     // nodes
#define NE   1600000    // edges
#define INF_ 128        // input features
#define HD   32         // hidden = HEADS*HEAD_D
#define TT   3          // edge types
#define LL   2          // layers

static const float RSQRT_D = 0.17677669529663687f;  // 1/sqrt(32)

// ---- monotone uint encoding of float for atomicMax-based segment max ----
__device__ __forceinline__ unsigned fkey(float f) {
    unsigned b = __float_as_uint(f);
    return (b & 0x80000000u) ? ~b : (b | 0x80000000u);
}
__device__ __forceinline__ float fkey_dec(unsigned k) {
    return (k & 0x80000000u) ? __uint_as_float(k & 0x7fffffffu)
                             : __uint_as_float(~k);
}

// h = x @ in_W + in_b   (block: 8 nodes x 32 dims)
__global__ void input_proj(const float* __restrict__ x,
                           const float* __restrict__ inW,
                           const float* __restrict__ inb,
                           float* __restrict__ h) {
    __shared__ float sW[INF_ * HD];   // 16 KB
    __shared__ float sx[8 * INF_];    // 4 KB
    for (int i = threadIdx.x; i < INF_ * HD; i += 256) sW[i] = inW[i];
    int node0 = blockIdx.x * 8;
    // stage 8 rows of x, vectorized (N % 8 == 0, grid exact)
    {
        const float4* xs = (const float4*)(x + (size_t)node0 * INF_);
        float4* dst4 = (float4*)sx;
        dst4[threadIdx.x] = xs[threadIdx.x];  // 256 * 16B = 8*128*4B
    }
    __syncthreads();
    int ln = threadIdx.x / HD, d = threadIdx.x % HD;
    int n = node0 + ln;
    float acc = inb[d];
    #pragma unroll
    for (int i = 0; i < INF_; ++i) acc += sx[ln * INF_ + i] * sW[i * HD + d];
    h[(size_t)n * HD + d] = acc;
}

// WkR[t] = Wk[l] @ Ratt[l,0,t];  WvR[t] = Wv[l] @ Rmsg[l,0,t]
__global__ void combine_mats(const float* __restrict__ Wk, const float* __restrict__ Wv,
                             const float* __restrict__ Ratt, const float* __restrict__ Rmsg,
                             float* __restrict__ WkR, float* __restrict__ WvR, int layer) {
    int idx = blockIdx.x * blockDim.x + threadIdx.x;   // 2*TT*32*32 = 6144
    if (idx >= 2 * TT * HD * HD) return;
    int which = idx / (TT * HD * HD);
    int r = idx % (TT * HD * HD);
    int t = r / (HD * HD);
    int ij = r % (HD * HD);
    int i = ij / HD, e = ij % HD;
    const float* W = (which ? Wv : Wk) + layer * HD * HD;
    const float* R = (which ? Rmsg : Ratt) + (size_t)(layer * TT + t) * HD * HD;
    float acc = 0.f;
    #pragma unroll
    for (int d = 0; d < HD; ++d) acc += W[i * HD + d] * R[d * HD + e];
    (which ? WvR : WkR)[t * HD * HD + ij] = acc;
}

// per node: q = h@Wq ; k_rel[t] = h@WkR[t] ; v_rel[t] = h@WvR[t]
__global__ void node_proj(const float* __restrict__ h, const float* __restrict__ Wq,
                          const float* __restrict__ WkR, const float* __restrict__ WvR,
                          float* __restrict__ q, float* __restrict__ k_rel,
                          float* __restrict__ v_rel, int layer) {
    __shared__ float sWq[HD * HD];
    __shared__ float sK[TT * HD * HD];
    __shared__ float sV[TT * HD * HD];
    __shared__ float sh[8 * HD];
    const float* wq = Wq + layer * HD * HD;
    for (int i = threadIdx.x; i < HD * HD; i += 256) sWq[i] = wq[i];
    for (int i = threadIdx.x; i < TT * HD * HD; i += 256) { sK[i] = WkR[i]; sV[i] = WvR[i]; }
    int node0 = blockIdx.x * 8;
    {
        const float4* hs = (const float4*)(h + (size_t)node0 * HD);
        float4* dst4 = (float4*)sh;
        if (threadIdx.x < 64) dst4[threadIdx.x] = hs[threadIdx.x];  // 8*32 floats
    }
    __syncthreads();
    int ln = threadIdx.x / HD, d = threadIdx.x % HD;
    int n = node0 + ln;
    float aq = 0.f;
    float ak0 = 0.f, ak1 = 0.f, ak2 = 0.f;
    float av0 = 0.f, av1 = 0.f, av2 = 0.f;
    #pragma unroll
    for (int i = 0; i < HD; ++i) {
        float hv = sh[ln * HD + i];
        aq  += hv * sWq[i * HD + d];
        ak0 += hv * sK[0 * HD * HD + i * HD + d];
        ak1 += hv * sK[1 * HD * HD + i * HD + d];
        ak2 += hv * sK[2 * HD * HD + i * HD + d];
        av0 += hv * sV[0 * HD * HD + i * HD + d];
        av1 += hv * sV[1 * HD * HD + i * HD + d];
        av2 += hv * sV[2 * HD * HD + i * HD + d];
    }
    q[(size_t)n * HD + d] = aq;
    k_rel[(0 * (size_t)NN + n) * HD + d] = ak0;
    k_rel[(1 * (size_t)NN + n) * HD + d] = ak1;
    k_rel[(2 * (size_t)NN + n) * HD + d] = ak2;
    v_rel[(0 * (size_t)NN + n) * HD + d] = av0;
    v_rel[(1 * (size_t)NN + n) * HD + d] = av1;
    v_rel[(2 * (size_t)NN + n) * HD + d] = av2;
}

__global__ void init_node_accum(unsigned* __restrict__ amax_key,
                                float* __restrict__ denom, float* __restrict__ agg) {
    int i = blockIdx.x * blockDim.x + threadIdx.x;
    if (i < NN * HD) agg[i] = 0.f;
    if (i < NN) { amax_key[i] = 0x00800000u; denom[i] = 0.f; }  // encode(-FLT_MAX)
}

// pass B: a[e] = dot(k_rel[t,src], q[dst]) * pri[t] / sqrt(d); segment max via atomicMax
__global__ void edge_logits(const int* __restrict__ src, const int* __restrict__ dst,
                            const int* __restrict__ etype,
                            const float* __restrict__ k_rel, const float* __restrict__ q,
                            const float* __restrict__ pri,
                            float* __restrict__ a, unsigned* __restrict__ amax_key,
                            int layer) {
    int e = blockIdx.x * blockDim.x + threadIdx.x;
    if (e >= NE) return;
    int s = src[e], dte = dst[e], t = etype[e];
    const float4* kr = (const float4*)(k_rel + ((size_t)t * NN + s) * HD);
    const float4* qq = (const float4*)(q + (size_t)dte * HD);
    float acc = 0.f;
    #pragma unroll
    for (int j = 0; j < HD / 4; ++j) {
        float4 kv = kr[j], qv = qq[j];
        acc += kv.x * qv.x + kv.y * qv.y + kv.z * qv.z + kv.w * qv.w;
    }
    float logit = acc * pri[layer * TT + t] * RSQRT_D;
    a[e] = logit;
    atomicMax(&amax_key[dte], fkey(logit));
}

// pass C: ea = exp(a - amax[dst]); denom[dst]+=ea; agg[dst]+=ea*v_rel[t,src]
__global__ void edge_agg(const int* __restrict__ src, const int* __restrict__ dst,
                         const int* __restrict__ etype,
                         const float* __restrict__ a, const unsigned* __restrict__ amax_key,
                         const float* __restrict__ v_rel,
                         float* __restrict__ denom, float* __restrict__ agg) {
    int e = blockIdx.x * blockDim.x + threadIdx.x;
    if (e >= NE) return;
    int s = src[e], dte = dst[e], t = etype[e];
    float amax = fkey_dec(amax_key[dte]);
    float ea = expf(a[e] - amax);
    atomicAdd(&denom[dte], ea);
    const float4* vr = (const float4*)(v_rel + ((size_t)t * NN + s) * HD);
    float* ag = agg + (size_t)dte * HD;
    #pragma unroll
    for (int j = 0; j < HD / 4; ++j) {
        float4 v = vr[j];
        atomicAdd(&ag[4 * j + 0], ea * v.x);
        atomicAdd(&ag[4 * j + 1], ea * v.y);
        atomicAdd(&ag[4 * j + 2], ea * v.z);
        atomicAdd(&ag[4 * j + 3], ea * v.w);
    }
}

// pass D: msg = agg/denom; out = msg @ Wa; h = relu(out*gate + h*(1-gate)) (in place)
__global__ void node_out(const float* __restrict__ Wa, const float* __restrict__ skip,
                         const float* __restrict__ denom, const float* __restrict__ agg,
                         float* __restrict__ h, int layer) {
    __shared__ float sWa[HD * HD];
    __shared__ float sm[8 * HD];
    const float* wa = Wa + layer * HD * HD;
    for (int i = threadIdx.x; i < HD * HD; i += 256) sWa[i] = wa[i];
    int node0 = blockIdx.x * 8;
    for (int i = threadIdx.x; i < 8 * HD; i += 256) {
        int nn = node0 + i / HD;
        float dn = denom[nn];
        sm[i] = (dn > 0.f) ? agg[(size_t)nn * HD + (i % HD)] / dn : 0.f;
    }
    __syncthreads();
    int ln = threadIdx.x / HD, d = threadIdx.x % HD;
    int n = node0 + ln;
    float acc = 0.f;
    #pragma unroll
    for (int i = 0; i < HD; ++i) acc += sm[ln * HD + i] * sWa[i * HD + d];
    float gate = 1.f / (1.f + expf(-skip[layer]));
    size_t idx = (size_t)n * HD + d;
    float o = acc * gate + h[idx] * (1.f - gate);
    h[idx] = fmaxf(o, 0.f);
}

// out = h @ mlp_W + mlp_b  (C=2)
__global__ void mlp_out(const float* __restrict__ h, const float* __restrict__ W,
                        const float* __restrict__ b, float* __restrict__ out) {
    int n = blockIdx.x * blockDim.x + threadIdx.x;
    if (n >= NN) return;
    const float4* hr = (const float4*)(h + (size_t)n * HD);
    float acc0 = b[0], acc1 = b[1];
    #pragma unroll
    for (int j = 0; j < HD / 4; ++j) {
        float4 hv = hr[j];
        acc0 += hv.x * W[(4 * j + 0) * 2 + 0] + hv.y * W[(4 * j + 1) * 2 + 0]
              + hv.z * W[(4 * j + 2) * 2 + 0] + hv.w * W[(4 * j + 3) * 2 + 0];
        acc1 += hv.x * W[(4 * j + 0) * 2 + 1] + hv.y * W[(4 * j + 1) * 2 + 1]
              + hv.z * W[(4 * j + 2) * 2 + 1] + hv.w * W[(4 * j + 3) * 2 + 1];
    }
    out[(size_t)n * 2 + 0] = acc0;
    out[(size_t)n * 2 + 1] = acc1;
}

extern "C" void kernel_launch(void* const* d_in, const int* in_sizes, int n_in,
                              void* d_out, int out_size, void* d_ws, size_t ws_size,
                              hipStream_t stream) {
    const float* x     = (const float*)d_in[0];
    const int*   src   = (const int*)d_in[1];
    const int*   dst   = (const int*)d_in[2];
    const int*   etype = (const int*)d_in[3];
    const float* in_W  = (const float*)d_in[4];
    const float* in_b  = (const float*)d_in[5];
    const float* Wk    = (const float*)d_in[6];
    const float* Wq    = (const float*)d_in[7];
    const float* Wv    = (const float*)d_in[8];
    const float* Wa    = (const float*)d_in[9];
    const float* pri   = (const float*)d_in[10];
    const float* Ratt  = (const float*)d_in[11];
    const float* Rmsg  = (const float*)d_in[12];
    const float* skip  = (const float*)d_in[13];
    const float* mlp_W = (const float*)d_in[14];
    const float* mlp_b = (const float*)d_in[15];
    float* out = (float*)d_out;

    float* ws = (float*)d_ws;
    float*    h        = ws;                          // N*HD
    float*    q        = h + (size_t)NN * HD;         // N*HD
    float*    k_rel    = q + (size_t)NN * HD;         // 3*N*HD
    float*    v_rel    = k_rel + (size_t)3 * NN * HD; // 3*N*HD
    float*    a        = v_rel + (size_t)3 * NN * HD; // E
    unsigned* amax_key = (unsigned*)(a + NE);         // N
    float*    denom    = (float*)(amax_key + NN);     // N
    float*    agg      = denom + NN;                  // N*HD
    float*    WkR      = agg + (size_t)NN * HD;       // 3*HD*HD
    float*    WvR      = WkR + TT * HD * HD;          // 3*HD*HD

    input_proj<<<NN / 8, 256, 0, stream>>>(x, in_W, in_b, h);
    for (int l = 0; l < LL; ++l) {
        combine_mats<<<(2 * TT * HD * HD + 255) / 256, 256, 0, stream>>>(
            Wk, Wv, Ratt, Rmsg, WkR, WvR, l);
        node_proj<<<NN / 8, 256, 0, stream>>>(h, Wq, WkR, WvR, q, k_rel, v_rel, l);
        init_node_accum<<<(NN * HD + 255) / 256, 256, 0, stream>>>(amax_key, denom, agg);
        edge_logits<<<(NE + 255) / 256, 256, 0, stream>>>(
            src, dst, etype, k_rel, q, pri, a, amax_key, l);
        edge_agg<<<(NE + 255) / 256, 256, 0, stream>>>(
            src, dst, etype, a, amax_key, v_rel, denom, agg);
        node_out<<<NN / 8, 256, 0, stream>>>(Wa, skip, denom, agg, h, l);
    }
    mlp_out<<<(NN + 255) / 256, 256, 0, stream>>>(h, mlp_W, mlp_b, out);
}

// Round 2
// 727.298 us; speedup vs baseline: 8.0559x; 8.0559x over previous
//
#include <hip/hip_runtime.h>

#define NN   100000     // nodes
#define NE   1600000    // edges
#define INF_ 128        // input features
#define HD   32         // hidden = HEADS*HEAD_D
#define TT   3          // edge types
#define LL   2          // layers
#define NBLK ((NN + 255) / 256)   // 391 scan blocks

static const float RSQRT_D = 0.17677669529663687f;  // 1/sqrt(32)

// h = x @ in_W + in_b   (block: 8 nodes x 32 dims)
__global__ void input_proj(const float* __restrict__ x,
                           const float* __restrict__ inW,
                           const float* __restrict__ inb,
                           float* __restrict__ h) {
    __shared__ float sW[INF_ * HD];   // 16 KB
    __shared__ float sx[8 * INF_];    // 4 KB
    for (int i = threadIdx.x; i < INF_ * HD; i += 256) sW[i] = inW[i];
    int node0 = blockIdx.x * 8;
    {
        const float4* xs = (const float4*)(x + (size_t)node0 * INF_);
        float4* dst4 = (float4*)sx;
        dst4[threadIdx.x] = xs[threadIdx.x];
    }
    __syncthreads();
    int ln = threadIdx.x / HD, d = threadIdx.x % HD;
    int n = node0 + ln;
    float acc = inb[d];
    #pragma unroll
    for (int i = 0; i < INF_; ++i) acc += sx[ln * INF_ + i] * sW[i * HD + d];
    h[(size_t)n * HD + d] = acc;
}

// ---------------- CSR build (once per call) ----------------
__global__ void init_csr(int* __restrict__ cnt, int* __restrict__ fill) {
    int i = blockIdx.x * blockDim.x + threadIdx.x;
    if (i < NN) { cnt[i] = 0; fill[i] = 0; }
}

__global__ void count_dst(const int* __restrict__ dst, int* __restrict__ cnt) {
    int e = blockIdx.x * blockDim.x + threadIdx.x;
    if (e < NE) atomicAdd(&cnt[dst[e]], 1);
}

// per-block exclusive scan; block sums out
__global__ void scan1(const int* __restrict__ cnt, int* __restrict__ rowptr,
                      int* __restrict__ bsum) {
    __shared__ int s[256];
    int i = blockIdx.x * 256 + threadIdx.x;
    int v = (i < NN) ? cnt[i] : 0;
    s[threadIdx.x] = v;
    __syncthreads();
    for (int off = 1; off < 256; off <<= 1) {
        int t = (threadIdx.x >= off) ? s[threadIdx.x - off] : 0;
        __syncthreads();
        s[threadIdx.x] += t;
        __syncthreads();
    }
    if (i < NN) rowptr[i] = s[threadIdx.x] - v;   // exclusive within block
    if (threadIdx.x == 255) bsum[blockIdx.x] = s[255];
}

// single-block scan of block sums
__global__ void scan2(const int* __restrict__ bsum, int* __restrict__ bofs) {
    __shared__ int s[512];
    int v = (threadIdx.x < NBLK) ? bsum[threadIdx.x] : 0;
    s[threadIdx.x] = v;
    __syncthreads();
    for (int off = 1; off < 512; off <<= 1) {
        int t = (threadIdx.x >= off) ? s[threadIdx.x - off] : 0;
        __syncthreads();
        s[threadIdx.x] += t;
        __syncthreads();
    }
    if (threadIdx.x < NBLK) bofs[threadIdx.x] = s[threadIdx.x] - v;  // exclusive
}

__global__ void scan3(int* __restrict__ rowptr, const int* __restrict__ bofs) {
    int i = blockIdx.x * 256 + threadIdx.x;
    if (i < NN) rowptr[i] += bofs[blockIdx.x];
    if (i == 0) rowptr[NN] = NE;
}

// scatter edges into CSR slots; record slot per edge and t*NN+src per slot
__global__ void scatter_edges(const int* __restrict__ src, const int* __restrict__ dst,
                              const int* __restrict__ etype,
                              const int* __restrict__ rowptr, int* __restrict__ fill,
                              int* __restrict__ epos, int* __restrict__ einfo) {
    int e = blockIdx.x * blockDim.x + threadIdx.x;
    if (e >= NE) return;
    int dn = dst[e];
    int p = rowptr[dn] + atomicAdd(&fill[dn], 1);
    epos[e] = p;
    einfo[p] = etype[e] * NN + src[e];
}

// ---------------- per-layer kernels ----------------

// WkR[t] = Wk[l] @ Ratt[l,0,t];  WvR[t] = Wv[l] @ Rmsg[l,0,t]
__global__ void combine_mats(const float* __restrict__ Wk, const float* __restrict__ Wv,
                             const float* __restrict__ Ratt, const float* __restrict__ Rmsg,
                             float* __restrict__ WkR, float* __restrict__ WvR, int layer) {
    int idx = blockIdx.x * blockDim.x + threadIdx.x;   // 6144
    if (idx >= 2 * TT * HD * HD) return;
    int which = idx / (TT * HD * HD);
    int r = idx % (TT * HD * HD);
    int t = r / (HD * HD);
    int ij = r % (HD * HD);
    int i = ij / HD, e = ij % HD;
    const float* W = (which ? Wv : Wk) + layer * HD * HD;
    const float* R = (which ? Rmsg : Ratt) + (size_t)(layer * TT + t) * HD * HD;
    float acc = 0.f;
    #pragma unroll
    for (int d = 0; d < HD; ++d) acc += W[i * HD + d] * R[d * HD + e];
    (which ? WvR : WkR)[t * HD * HD + ij] = acc;
}

// per node: q = h@Wq ; k_rel[t] = h@WkR[t] ; v_rel[t] = h@WvR[t]
__global__ void node_proj(const float* __restrict__ h, const float* __restrict__ Wq,
                          const float* __restrict__ WkR, const float* __restrict__ WvR,
                          float* __restrict__ q, float* __restrict__ k_rel,
                          float* __restrict__ v_rel, int layer) {
    __shared__ float sWq[HD * HD];
    __shared__ float sK[TT * HD * HD];
    __shared__ float sV[TT * HD * HD];
    __shared__ float sh[8 * HD];
    const float* wq = Wq + layer * HD * HD;
    for (int i = threadIdx.x; i < HD * HD; i += 256) sWq[i] = wq[i];
    for (int i = threadIdx.x; i < TT * HD * HD; i += 256) { sK[i] = WkR[i]; sV[i] = WvR[i]; }
    int node0 = blockIdx.x * 8;
    {
        const float4* hs = (const float4*)(h + (size_t)node0 * HD);
        float4* dst4 = (float4*)sh;
        if (threadIdx.x < 64) dst4[threadIdx.x] = hs[threadIdx.x];
    }
    __syncthreads();
    int ln = threadIdx.x / HD, d = threadIdx.x % HD;
    int n = node0 + ln;
    float aq = 0.f;
    float ak0 = 0.f, ak1 = 0.f, ak2 = 0.f;
    float av0 = 0.f, av1 = 0.f, av2 = 0.f;
    #pragma unroll
    for (int i = 0; i < HD; ++i) {
        float hv = sh[ln * HD + i];
        aq  += hv * sWq[i * HD + d];
        ak0 += hv * sK[0 * HD * HD + i * HD + d];
        ak1 += hv * sK[1 * HD * HD + i * HD + d];
        ak2 += hv * sK[2 * HD * HD + i * HD + d];
        av0 += hv * sV[0 * HD * HD + i * HD + d];
        av1 += hv * sV[1 * HD * HD + i * HD + d];
        av2 += hv * sV[2 * HD * HD + i * HD + d];
    }
    q[(size_t)n * HD + d] = aq;
    k_rel[(0 * (size_t)NN + n) * HD + d] = ak0;
    k_rel[(1 * (size_t)NN + n) * HD + d] = ak1;
    k_rel[(2 * (size_t)NN + n) * HD + d] = ak2;
    v_rel[(0 * (size_t)NN + n) * HD + d] = av0;
    v_rel[(1 * (size_t)NN + n) * HD + d] = av1;
    v_rel[(2 * (size_t)NN + n) * HD + d] = av2;
}

// logits written directly into CSR slots; no atomics
__global__ void edge_logits(const int* __restrict__ src, const int* __restrict__ dst,
                            const int* __restrict__ etype, const int* __restrict__ epos,
                            const float* __restrict__ k_rel, const float* __restrict__ q,
                            const float* __restrict__ pri,
                            float* __restrict__ a_csr, int layer) {
    int e = blockIdx.x * blockDim.x + threadIdx.x;
    if (e >= NE) return;
    int s = src[e], dn = dst[e], t = etype[e];
    const float4* kr = (const float4*)(k_rel + ((size_t)t * NN + s) * HD);
    const float4* qq = (const float4*)(q + (size_t)dn * HD);
    float acc = 0.f;
    #pragma unroll
    for (int j = 0; j < HD / 4; ++j) {
        float4 kv = kr[j], qv = qq[j];
        acc += kv.x * qv.x + kv.y * qv.y + kv.z * qv.z + kv.w * qv.w;
    }
    a_csr[epos[e]] = acc * pri[layer * TT + t] * RSQRT_D;
}

// per-node softmax + aggregation + Wa + gate + relu, fused.
// 256 threads = 4 waves; each wave handles 2 nodes (32 lanes per node, lane=dim)
__global__ void node_agg_out(const int* __restrict__ rowptr, const int* __restrict__ einfo,
                             const float* __restrict__ a_csr, const float* __restrict__ v_rel,
                             const float* __restrict__ Wa, const float* __restrict__ skip,
                             float* __restrict__ h, int layer) {
    __shared__ float sWa[HD * HD];
    __shared__ float sm[8 * HD];
    const float* wa = Wa + layer * HD * HD;
    for (int i = threadIdx.x; i < HD * HD; i += 256) sWa[i] = wa[i];
    int lane = threadIdx.x & 63;
    int d = lane & 31;
    int nloc = (threadIdx.x >> 6) * 2 + (lane >> 5);   // 0..7
    int n = blockIdx.x * 8 + nloc;
    int r0 = rowptr[n], r1 = rowptr[n + 1];
    // pass 1: segment max (lanes parallel over slots, then 32-lane reduce)
    float m = -__builtin_inff();
    for (int i = r0 + d; i < r1; i += 32) m = fmaxf(m, a_csr[i]);
    #pragma unroll
    for (int off = 16; off; off >>= 1) m = fmaxf(m, __shfl_xor(m, off));
    // pass 2: denom + weighted aggregation (lanes parallel over dims)
    float den = 0.f, acc = 0.f;
    for (int i = r0; i < r1; ++i) {
        float ea = __expf(a_csr[i] - m);     // broadcast load, redundant exp
        den += ea;
        int sid = einfo[i];
        acc += ea * v_rel[(size_t)sid * HD + d];
    }
    sm[nloc * HD + d] = (r1 > r0) ? acc / den : 0.f;
    __syncthreads();
    float o = 0.f;
    #pragma unroll
    for (int i = 0; i < HD; ++i) o += sm[nloc * HD + i] * sWa[i * HD + d];
    float gate = 1.f / (1.f + __expf(-skip[layer]));
    size_t idx = (size_t)n * HD + d;
    float val = o * gate + h[idx] * (1.f - gate);
    h[idx] = fmaxf(val, 0.f);
}

// out = h @ mlp_W + mlp_b  (C=2)
__global__ void mlp_out(const float* __restrict__ h, const float* __restrict__ W,
                        const float* __restrict__ b, float* __restrict__ out) {
    int n = blockIdx.x * blockDim.x + threadIdx.x;
    if (n >= NN) return;
    const float4* hr = (const float4*)(h + (size_t)n * HD);
    float acc0 = b[0], acc1 = b[1];
    #pragma unroll
    for (int j = 0; j < HD / 4; ++j) {
        float4 hv = hr[j];
        acc0 += hv.x * W[(4 * j + 0) * 2 + 0] + hv.y * W[(4 * j + 1) * 2 + 0]
              + hv.z * W[(4 * j + 2) * 2 + 0] + hv.w * W[(4 * j + 3) * 2 + 0];
        acc1 += hv.x * W[(4 * j + 0) * 2 + 1] + hv.y * W[(4 * j + 1) * 2 + 1]
              + hv.z * W[(4 * j + 2) * 2 + 1] + hv.w * W[(4 * j + 3) * 2 + 1];
    }
    out[(size_t)n * 2 + 0] = acc0;
    out[(size_t)n * 2 + 1] = acc1;
}

extern "C" void kernel_launch(void* const* d_in, const int* in_sizes, int n_in,
                              void* d_out, int out_size, void* d_ws, size_t ws_size,
                              hipStream_t stream) {
    const float* x     = (const float*)d_in[0];
    const int*   src   = (const int*)d_in[1];
    const int*   dst   = (const int*)d_in[2];
    const int*   etype = (const int*)d_in[3];
    const float* in_W  = (const float*)d_in[4];
    const float* in_b  = (const float*)d_in[5];
    const float* Wk    = (const float*)d_in[6];
    const float* Wq    = (const float*)d_in[7];
    const float* Wv    = (const float*)d_in[8];
    const float* Wa    = (const float*)d_in[9];
    const float* pri   = (const float*)d_in[10];
    const float* Ratt  = (const float*)d_in[11];
    const float* Rmsg  = (const float*)d_in[12];
    const float* skip  = (const float*)d_in[13];
    const float* mlp_W = (const float*)d_in[14];
    const float* mlp_b = (const float*)d_in[15];
    float* out = (float*)d_out;

    float* ws = (float*)d_ws;
    float* h      = ws;                            // NN*HD
    float* q      = h + (size_t)NN * HD;           // NN*HD
    float* k_rel  = q + (size_t)NN * HD;           // 3*NN*HD
    float* v_rel  = k_rel + (size_t)3 * NN * HD;   // 3*NN*HD
    float* a_csr  = v_rel + (size_t)3 * NN * HD;   // NE
    float* WkR    = a_csr + NE;                    // 3*HD*HD
    float* WvR    = WkR + TT * HD * HD;            // 3*HD*HD
    int* rowptr   = (int*)(WvR + TT * HD * HD);    // NN+1
    int* cnt      = rowptr + NN + 1;               // NN
    int* fill     = cnt + NN;                      // NN
    int* bsum     = fill + NN;                     // 512
    int* bofs     = bsum + 512;                    // 512
    int* epos     = bofs + 512;                    // NE
    int* einfo    = epos + NE;                     // NE

    input_proj<<<NN / 8, 256, 0, stream>>>(x, in_W, in_b, h);

    // CSR build (edge structure is layer-invariant)
    init_csr<<<NBLK, 256, 0, stream>>>(cnt, fill);
    count_dst<<<(NE + 255) / 256, 256, 0, stream>>>(dst, cnt);
    scan1<<<NBLK, 256, 0, stream>>>(cnt, rowptr, bsum);
    scan2<<<1, 512, 0, stream>>>(bsum, bofs);
    scan3<<<NBLK, 256, 0, stream>>>(rowptr, bofs);
    scatter_edges<<<(NE + 255) / 256, 256, 0, stream>>>(src, dst, etype, rowptr, fill,
                                                        epos, einfo);

    for (int l = 0; l < LL; ++l) {
        combine_mats<<<(2 * TT * HD * HD + 255) / 256, 256, 0, stream>>>(
            Wk, Wv, Ratt, Rmsg, WkR, WvR, l);
        node_proj<<<NN / 8, 256, 0, stream>>>(h, Wq, WkR, WvR, q, k_rel, v_rel, l);
        edge_logits<<<(NE + 255) / 256, 256, 0, stream>>>(
            src, dst, etype, epos, k_rel, q, pri, a_csr, l);
        node_agg_out<<<NN / 8, 256, 0, stream>>>(
            rowptr, einfo, a_csr, v_rel, Wa, skip, h, l);
    }
    mlp_out<<<(NN + 255) / 256, 256, 0, stream>>>(h, mlp_W, mlp_b, out);
}

// Round 3
// 620.355 us; speedup vs baseline: 9.4447x; 1.1724x over previous
//
#include <hip/hip_runtime.h>

#define NN   100000     // nodes
#define NE   1600000    // edges
#define INF_ 128        // input features
#define HD   32         // hidden = HEADS*HEAD_D
#define TT   3          // edge types
#define LL   2          // layers
#define NBLK ((NN + 255) / 256)   // 391 scan blocks
#define PSLICE 128                // edge slices per dst-range in partitioned passes

static const float RSQRT_D = 0.17677669529663687f;  // 1/sqrt(32)

// h = x @ in_W + in_b   (block: 8 nodes x 32 dims)
__global__ void input_proj(const float* __restrict__ x,
                           const float* __restrict__ inW,
                           const float* __restrict__ inb,
                           float* __restrict__ h) {
    __shared__ float sW[INF_ * HD];   // 16 KB
    __shared__ float sx[8 * INF_];    // 4 KB
    for (int i = threadIdx.x; i < INF_ * HD; i += 256) sW[i] = inW[i];
    int node0 = blockIdx.x * 8;
    {
        const float4* xs = (const float4*)(x + (size_t)node0 * INF_);
        float4* dst4 = (float4*)sx;
        dst4[threadIdx.x] = xs[threadIdx.x];
    }
    __syncthreads();
    int ln = threadIdx.x / HD, d = threadIdx.x % HD;
    int n = node0 + ln;
    float acc = inb[d];
    #pragma unroll
    for (int i = 0; i < INF_; ++i) acc += sx[ln * INF_ + i] * sW[i * HD + d];
    h[(size_t)n * HD + d] = acc;
}

// ---------------- CSR build (once per call, XCD-partitioned by dst range) ----------------
__global__ void init_csr(int* __restrict__ cnt, int* __restrict__ fill) {
    int i = blockIdx.x * blockDim.x + threadIdx.x;
    if (i < NN) { cnt[i] = 0; fill[i] = 0; }
}

// each block owns dst-range (blockIdx & 7); atomics stay in one XCD's L2
__global__ void count_dst_part(const int* __restrict__ dst, int* __restrict__ cnt) {
    int r = blockIdx.x & 7;
    int s = blockIdx.x >> 3;
    int lo = r * (NN / 8), hi = lo + NN / 8;
    for (int e = s * 256 + threadIdx.x; e < NE; e += PSLICE * 256) {
        int dn = dst[e];
        if (dn >= lo && dn < hi) atomicAdd(&cnt[dn], 1);
    }
}

// per-block exclusive scan; block sums out
__global__ void scan1(const int* __restrict__ cnt, int* __restrict__ rowptr,
                      int* __restrict__ bsum) {
    __shared__ int s[256];
    int i = blockIdx.x * 256 + threadIdx.x;
    int v = (i < NN) ? cnt[i] : 0;
    s[threadIdx.x] = v;
    __syncthreads();
    for (int off = 1; off < 256; off <<= 1) {
        int t = (threadIdx.x >= off) ? s[threadIdx.x - off] : 0;
        __syncthreads();
        s[threadIdx.x] += t;
        __syncthreads();
    }
    if (i < NN) rowptr[i] = s[threadIdx.x] - v;
    if (threadIdx.x == 255) bsum[blockIdx.x] = s[255];
}

__global__ void scan2(const int* __restrict__ bsum, int* __restrict__ bofs) {
    __shared__ int s[512];
    int v = (threadIdx.x < NBLK) ? bsum[threadIdx.x] : 0;
    s[threadIdx.x] = v;
    __syncthreads();
    for (int off = 1; off < 512; off <<= 1) {
        int t = (threadIdx.x >= off) ? s[threadIdx.x - off] : 0;
        __syncthreads();
        s[threadIdx.x] += t;
        __syncthreads();
    }
    if (threadIdx.x < NBLK) bofs[threadIdx.x] = s[threadIdx.x] - v;
}

__global__ void scan3(int* __restrict__ rowptr, const int* __restrict__ bofs) {
    int i = blockIdx.x * 256 + threadIdx.x;
    if (i < NN) rowptr[i] += bofs[blockIdx.x];
    if (i == 0) rowptr[NN] = NE;
}

// scatter (src,etype) packed into CSR slots; partitioned so einfo writes are XCD-local
__global__ void scatter_part(const int* __restrict__ src, const int* __restrict__ dst,
                             const int* __restrict__ etype,
                             const int* __restrict__ rowptr, int* __restrict__ fill,
                             int* __restrict__ einfo) {
    int r = blockIdx.x & 7;
    int s = blockIdx.x >> 3;
    int lo = r * (NN / 8), hi = lo + NN / 8;
    for (int e = s * 256 + threadIdx.x; e < NE; e += PSLICE * 256) {
        int dn = dst[e];
        if (dn >= lo && dn < hi) {
            int p = rowptr[dn] + atomicAdd(&fill[dn], 1);
            einfo[p] = (src[e] << 2) | etype[e];
        }
    }
}

// dcsr[p] = owning dst node
__global__ void fill_dcsr(const int* __restrict__ rowptr, int* __restrict__ dcsr) {
    int n = blockIdx.x * 256 + threadIdx.x;
    if (n >= NN) return;
    int r1 = rowptr[n + 1];
    for (int p = rowptr[n]; p < r1; ++p) dcsr[p] = n;
}

// ---------------- per-layer kernels ----------------

// WqR[t] = Wq_l @ Ratt_t^T * pri_t / sqrt(d);  RW[t] = Rmsg_t @ Wa_l
__global__ void combine_mats2(const float* __restrict__ Wq, const float* __restrict__ Ratt,
                              const float* __restrict__ Rmsg, const float* __restrict__ Wa,
                              const float* __restrict__ pri,
                              float* __restrict__ WqR, float* __restrict__ RW, int layer) {
    int idx = blockIdx.x * blockDim.x + threadIdx.x;   // 6144
    if (idx >= 2 * TT * HD * HD) return;
    int which = idx / (TT * HD * HD);
    int rr = idx % (TT * HD * HD);
    int t = rr / (HD * HD);
    int ij = rr % (HD * HD);
    int i = ij / HD, j = ij % HD;
    if (which == 0) {
        const float* wq = Wq + layer * HD * HD;
        const float* ra = Ratt + (size_t)(layer * TT + t) * HD * HD;
        float acc = 0.f;
        #pragma unroll
        for (int e = 0; e < HD; ++e) acc += wq[i * HD + e] * ra[j * HD + e];
        WqR[t * HD * HD + ij] = acc * pri[layer * TT + t] * RSQRT_D;
    } else {
        const float* rm = Rmsg + (size_t)(layer * TT + t) * HD * HD;
        const float* wa = Wa + layer * HD * HD;
        float acc = 0.f;
        #pragma unroll
        for (int e = 0; e < HD; ++e) acc += rm[i * HD + e] * wa[e * HD + j];
        RW[t * HD * HD + ij] = acc;
    }
}

// per node: k = h@Wk ; v = h@Wv ; q_rel[t] = h@WqR[t]
__global__ void node_proj5(const float* __restrict__ h, const float* __restrict__ Wk,
                           const float* __restrict__ Wv, const float* __restrict__ WqR,
                           float* __restrict__ k, float* __restrict__ v,
                           float* __restrict__ q_rel, int layer) {
    __shared__ float sK[HD * HD];
    __shared__ float sV[HD * HD];
    __shared__ float sQ[TT * HD * HD];
    __shared__ float sh[8 * HD];
    const float* wk = Wk + layer * HD * HD;
    const float* wv = Wv + layer * HD * HD;
    for (int i = threadIdx.x; i < HD * HD; i += 256) { sK[i] = wk[i]; sV[i] = wv[i]; }
    for (int i = threadIdx.x; i < TT * HD * HD; i += 256) sQ[i] = WqR[i];
    int node0 = blockIdx.x * 8;
    {
        const float4* hs = (const float4*)(h + (size_t)node0 * HD);
        float4* dst4 = (float4*)sh;
        if (threadIdx.x < 64) dst4[threadIdx.x] = hs[threadIdx.x];
    }
    __syncthreads();
    int ln = threadIdx.x / HD, d = threadIdx.x % HD;
    int n = node0 + ln;
    float ak = 0.f, av = 0.f, a0 = 0.f, a1 = 0.f, a2 = 0.f;
    #pragma unroll
    for (int i = 0; i < HD; ++i) {
        float hv = sh[ln * HD + i];
        ak += hv * sK[i * HD + d];
        av += hv * sV[i * HD + d];
        a0 += hv * sQ[0 * HD * HD + i * HD + d];
        a1 += hv * sQ[1 * HD * HD + i * HD + d];
        a2 += hv * sQ[2 * HD * HD + i * HD + d];
    }
    k[(size_t)n * HD + d] = ak;
    v[(size_t)n * HD + d] = av;
    q_rel[(0 * (size_t)NN + n) * HD + d] = a0;
    q_rel[(1 * (size_t)NN + n) * HD + d] = a1;
    q_rel[(2 * (size_t)NN + n) * HD + d] = a2;
}

// logits in CSR slot order: 8 lanes per slot, coalesced einfo/dcsr/a_csr
__global__ void edge_logits_csr(const int* __restrict__ einfo, const int* __restrict__ dcsr,
                                const float* __restrict__ k, const float* __restrict__ q_rel,
                                float* __restrict__ a_csr) {
    int p = blockIdx.x * 32 + (threadIdx.x >> 3);
    if (p >= NE) return;
    int g = threadIdx.x & 7;
    int sid = einfo[p];
    int srcn = sid >> 2, t = sid & 3;
    int dn = dcsr[p];
    float4 kv = *(const float4*)(k + (size_t)srcn * HD + 4 * g);
    float4 qv = *(const float4*)(q_rel + ((size_t)t * NN + dn) * HD + 4 * g);
    float acc = kv.x * qv.x + kv.y * qv.y + kv.z * qv.z + kv.w * qv.w;
    acc += __shfl_xor(acc, 1);
    acc += __shfl_xor(acc, 2);
    acc += __shfl_xor(acc, 4);
    if (g == 0) a_csr[p] = acc;
}

// per-node softmax + per-type aggregation of RAW v + (Rmsg_t@Wa) + gate + relu
__global__ void node_agg_out2(const int* __restrict__ rowptr, const int* __restrict__ einfo,
                              const float* __restrict__ a_csr, const float* __restrict__ v,
                              const float* __restrict__ RW, const float* __restrict__ skip,
                              float* __restrict__ h, int layer) {
    __shared__ float sRW[TT * HD * HD];   // 12 KB
    __shared__ float su[8 * TT * HD];     // 3 KB
    for (int i = threadIdx.x; i < TT * HD * HD; i += 256) sRW[i] = RW[i];
    int lane = threadIdx.x & 63;
    int d = lane & 31;
    int nloc = (threadIdx.x >> 6) * 2 + (lane >> 5);
    int n = blockIdx.x * 8 + nloc;
    int r0 = rowptr[n], r1 = rowptr[n + 1];
    float m = -__builtin_inff();
    for (int i = r0 + d; i < r1; i += 32) m = fmaxf(m, a_csr[i]);
    #pragma unroll
    for (int off = 16; off; off >>= 1) m = fmaxf(m, __shfl_xor(m, off));
    float den = 0.f, u0 = 0.f, u1 = 0.f, u2 = 0.f;
    for (int i = r0; i < r1; ++i) {
        float ea = __expf(a_csr[i] - m);
        den += ea;
        int sid = einfo[i];
        int srcn = sid >> 2, t = sid & 3;
        float eav = ea * v[(size_t)srcn * HD + d];
        u0 += (t == 0) ? eav : 0.f;
        u1 += (t == 1) ? eav : 0.f;
        u2 += (t == 2) ? eav : 0.f;
    }
    float inv = (r1 > r0) ? 1.f / den : 0.f;
    su[(nloc * TT + 0) * HD + d] = u0 * inv;
    su[(nloc * TT + 1) * HD + d] = u1 * inv;
    su[(nloc * TT + 2) * HD + d] = u2 * inv;
    __syncthreads();
    float o = 0.f;
    #pragma unroll
    for (int t = 0; t < TT; ++t)
        #pragma unroll
        for (int i = 0; i < HD; ++i)
            o += su[(nloc * TT + t) * HD + i] * sRW[(t * HD + i) * HD + d];
    float gate = 1.f / (1.f + __expf(-skip[layer]));
    size_t idx = (size_t)n * HD + d;
    float val = o * gate + h[idx] * (1.f - gate);
    h[idx] = fmaxf(val, 0.f);
}

// out = h @ mlp_W + mlp_b  (C=2)
__global__ void mlp_out(const float* __restrict__ h, const float* __restrict__ W,
                        const float* __restrict__ b, float* __restrict__ out) {
    int n = blockIdx.x * blockDim.x + threadIdx.x;
    if (n >= NN) return;
    const float4* hr = (const float4*)(h + (size_t)n * HD);
    float acc0 = b[0], acc1 = b[1];
    #pragma unroll
    for (int j = 0; j < HD / 4; ++j) {
        float4 hv = hr[j];
        acc0 += hv.x * W[(4 * j + 0) * 2 + 0] + hv.y * W[(4 * j + 1) * 2 + 0]
              + hv.z * W[(4 * j + 2) * 2 + 0] + hv.w * W[(4 * j + 3) * 2 + 0];
        acc1 += hv.x * W[(4 * j + 0) * 2 + 1] + hv.y * W[(4 * j + 1) * 2 + 1]
              + hv.z * W[(4 * j + 2) * 2 + 1] + hv.w * W[(4 * j + 3) * 2 + 1];
    }
    out[(size_t)n * 2 + 0] = acc0;
    out[(size_t)n * 2 + 1] = acc1;
}

extern "C" void kernel_launch(void* const* d_in, const int* in_sizes, int n_in,
                              void* d_out, int out_size, void* d_ws, size_t ws_size,
                              hipStream_t stream) {
    const float* x     = (const float*)d_in[0];
    const int*   src   = (const int*)d_in[1];
    const int*   dst   = (const int*)d_in[2];
    const int*   etype = (const int*)d_in[3];
    const float* in_W  = (const float*)d_in[4];
    const float* in_b  = (const float*)d_in[5];
    const float* Wk    = (const float*)d_in[6];
    const float* Wq    = (const float*)d_in[7];
    const float* Wv    = (const float*)d_in[8];
    const float* Wa    = (const float*)d_in[9];
    const float* pri   = (const float*)d_in[10];
    const float* Ratt  = (const float*)d_in[11];
    const float* Rmsg  = (const float*)d_in[12];
    const float* skip  = (const float*)d_in[13];
    const float* mlp_W = (const float*)d_in[14];
    const float* mlp_b = (const float*)d_in[15];
    float* out = (float*)d_out;

    float* ws = (float*)d_ws;
    float* h      = ws;                            // NN*HD
    float* k      = h + (size_t)NN * HD;           // NN*HD
    float* v      = k + (size_t)NN * HD;           // NN*HD
    float* q_rel  = v + (size_t)NN * HD;           // 3*NN*HD
    float* a_csr  = q_rel + (size_t)3 * NN * HD;   // NE
    float* WqR    = a_csr + NE;                    // 3*HD*HD
    float* RW     = WqR + TT * HD * HD;            // 3*HD*HD
    int* rowptr   = (int*)(RW + TT * HD * HD);     // NN+1
    int* cnt      = rowptr + NN + 1;               // NN
    int* fill     = cnt + NN;                      // NN
    int* bsum     = fill + NN;                     // 512
    int* bofs     = bsum + 512;                    // 512
    int* einfo    = bofs + 512;                    // NE
    int* dcsr     = einfo + NE;                    // NE

    input_proj<<<NN / 8, 256, 0, stream>>>(x, in_W, in_b, h);

    init_csr<<<NBLK, 256, 0, stream>>>(cnt, fill);
    count_dst_part<<<8 * PSLICE, 256, 0, stream>>>(dst, cnt);
    scan1<<<NBLK, 256, 0, stream>>>(cnt, rowptr, bsum);
    scan2<<<1, 512, 0, stream>>>(bsum, bofs);
    scan3<<<NBLK, 256, 0, stream>>>(rowptr, bofs);
    scatter_part<<<8 * PSLICE, 256, 0, stream>>>(src, dst, etype, rowptr, fill, einfo);
    fill_dcsr<<<NBLK, 256, 0, stream>>>(rowptr, dcsr);

    for (int l = 0; l < LL; ++l) {
        combine_mats2<<<(2 * TT * HD * HD + 255) / 256, 256, 0, stream>>>(
            Wq, Ratt, Rmsg, Wa, pri, WqR, RW, l);
        node_proj5<<<NN / 8, 256, 0, stream>>>(h, Wk, Wv, WqR, k, v, q_rel, l);
        edge_logits_csr<<<(NE + 31) / 32, 256, 0, stream>>>(einfo, dcsr, k, q_rel, a_csr);
        node_agg_out2<<<NN / 8, 256, 0, stream>>>(rowptr, einfo, a_csr, v, RW, skip, h, l);
    }
    mlp_out<<<(NN + 255) / 256, 256, 0, stream>>>(h, mlp_W, mlp_b, out);
}

// Round 4
// 560.993 us; speedup vs baseline: 10.4441x; 1.1058x over previous
//
#include <hip/hip_runtime.h>

#define NN   100000     // nodes
#define NE   1600000    // edges
#define INF_ 128        // input features
#define HD   32         // hidden = HEADS*HEAD_D
#define TT   3          // edge types
#define LL   2          // layers
#define MM   (NN * TT)  // (dst,type) segments = 300000
#define NBLK  ((NN + 255) / 256)
#define NBLK2 ((MM + 1023) / 1024)   // 293 scan blocks over segments
#define PSLICE 128                   // edge slices per dst-range in partitioned passes

static const float RSQRT_D = 0.17677669529663687f;  // 1/sqrt(32)

// h = x @ in_W + in_b   (block: 8 nodes x 32 dims)
__global__ void input_proj(const float* __restrict__ x,
                           const float* __restrict__ inW,
                           const float* __restrict__ inb,
                           float* __restrict__ h) {
    __shared__ float sW[INF_ * HD];   // 16 KB
    __shared__ float sx[8 * INF_];    // 4 KB
    for (int i = threadIdx.x; i < INF_ * HD; i += 256) sW[i] = inW[i];
    int node0 = blockIdx.x * 8;
    {
        const float4* xs = (const float4*)(x + (size_t)node0 * INF_);
        float4* dst4 = (float4*)sx;
        dst4[threadIdx.x] = xs[threadIdx.x];
    }
    __syncthreads();
    int ln = threadIdx.x / HD, d = threadIdx.x % HD;
    int n = node0 + ln;
    float acc = inb[d];
    #pragma unroll
    for (int i = 0; i < INF_; ++i) acc += sx[ln * INF_ + i] * sW[i * HD + d];
    h[(size_t)n * HD + d] = acc;
}

// ------------- CSR build keyed by seg = dst*3 + etype (XCD-partitioned) -------------
__global__ void init_csr(int* __restrict__ cnt, int* __restrict__ fill) {
    int i = blockIdx.x * blockDim.x + threadIdx.x;
    if (i < MM) { cnt[i] = 0; fill[i] = 0; }
}

__global__ void count_dst_part(const int* __restrict__ dst, const int* __restrict__ etype,
                               int* __restrict__ cnt) {
    int r = blockIdx.x & 7;
    int s = blockIdx.x >> 3;
    int lo = r * (NN / 8), hi = lo + NN / 8;
    for (int e = s * 256 + threadIdx.x; e < NE; e += PSLICE * 256) {
        int dn = dst[e];
        if (dn >= lo && dn < hi) atomicAdd(&cnt[dn * TT + etype[e]], 1);
    }
}

// per-block (1024 threads) exclusive scan over MM entries; block sums out
__global__ void scan1(const int* __restrict__ cnt, int* __restrict__ rowptr,
                      int* __restrict__ bsum) {
    __shared__ int s[1024];
    int i = blockIdx.x * 1024 + threadIdx.x;
    int v = (i < MM) ? cnt[i] : 0;
    s[threadIdx.x] = v;
    __syncthreads();
    for (int off = 1; off < 1024; off <<= 1) {
        int t = (threadIdx.x >= off) ? s[threadIdx.x - off] : 0;
        __syncthreads();
        s[threadIdx.x] += t;
        __syncthreads();
    }
    if (i < MM) rowptr[i] = s[threadIdx.x] - v;
    if (threadIdx.x == 1023) bsum[blockIdx.x] = s[1023];
}

__global__ void scan2(const int* __restrict__ bsum, int* __restrict__ bofs) {
    __shared__ int s[512];
    int v = (threadIdx.x < NBLK2) ? bsum[threadIdx.x] : 0;
    s[threadIdx.x] = v;
    __syncthreads();
    for (int off = 1; off < 512; off <<= 1) {
        int t = (threadIdx.x >= off) ? s[threadIdx.x - off] : 0;
        __syncthreads();
        s[threadIdx.x] += t;
        __syncthreads();
    }
    if (threadIdx.x < NBLK2) bofs[threadIdx.x] = s[threadIdx.x] - v;
}

__global__ void scan3(int* __restrict__ rowptr, const int* __restrict__ bofs) {
    int i = blockIdx.x * 1024 + threadIdx.x;
    if (i < MM) rowptr[i] += bofs[blockIdx.x];
    if (i == 0) rowptr[MM] = NE;
}

// scatter (src,etype) packed into CSR slots; partitioned so writes stay XCD-local
__global__ void scatter_part(const int* __restrict__ src, const int* __restrict__ dst,
                             const int* __restrict__ etype,
                             const int* __restrict__ rowptr, int* __restrict__ fill,
                             int* __restrict__ einfo) {
    int r = blockIdx.x & 7;
    int s = blockIdx.x >> 3;
    int lo = r * (NN / 8), hi = lo + NN / 8;
    for (int e = s * 256 + threadIdx.x; e < NE; e += PSLICE * 256) {
        int dn = dst[e];
        if (dn >= lo && dn < hi) {
            int t = etype[e];
            int seg = dn * TT + t;
            int p = rowptr[seg] + atomicAdd(&fill[seg], 1);
            einfo[p] = (src[e] << 2) | t;
        }
    }
}

// dcsr[p] = owning dst node (full node range is contiguous: [rp[3n], rp[3n+3]))
__global__ void fill_dcsr(const int* __restrict__ rowptr, int* __restrict__ dcsr) {
    int n = blockIdx.x * 256 + threadIdx.x;
    if (n >= NN) return;
    int r1 = rowptr[TT * n + TT];
    for (int p = rowptr[TT * n]; p < r1; ++p) dcsr[p] = n;
}

// ---------------- per-layer kernels ----------------

// WqR[t] = Wq_l @ Ratt_t^T * pri_t / sqrt(d);  RW[t] = Rmsg_t @ Wa_l
__global__ void combine_mats2(const float* __restrict__ Wq, const float* __restrict__ Ratt,
                              const float* __restrict__ Rmsg, const float* __restrict__ Wa,
                              const float* __restrict__ pri,
                              float* __restrict__ WqR, float* __restrict__ RW, int layer) {
    int idx = blockIdx.x * blockDim.x + threadIdx.x;   // 6144
    if (idx >= 2 * TT * HD * HD) return;
    int which = idx / (TT * HD * HD);
    int rr = idx % (TT * HD * HD);
    int t = rr / (HD * HD);
    int ij = rr % (HD * HD);
    int i = ij / HD, j = ij % HD;
    if (which == 0) {
        const float* wq = Wq + layer * HD * HD;
        const float* ra = Ratt + (size_t)(layer * TT + t) * HD * HD;
        float acc = 0.f;
        #pragma unroll
        for (int e = 0; e < HD; ++e) acc += wq[i * HD + e] * ra[j * HD + e];
        WqR[t * HD * HD + ij] = acc * pri[layer * TT + t] * RSQRT_D;
    } else {
        const float* rm = Rmsg + (size_t)(layer * TT + t) * HD * HD;
        const float* wa = Wa + layer * HD * HD;
        float acc = 0.f;
        #pragma unroll
        for (int e = 0; e < HD; ++e) acc += rm[i * HD + e] * wa[e * HD + j];
        RW[t * HD * HD + ij] = acc;
    }
}

// per node: k = h@Wk ; v = h@Wv ; q_rel[t] = h@WqR[t]
__global__ void node_proj5(const float* __restrict__ h, const float* __restrict__ Wk,
                           const float* __restrict__ Wv, const float* __restrict__ WqR,
                           float* __restrict__ k, float* __restrict__ v,
                           float* __restrict__ q_rel, int layer) {
    __shared__ float sK[HD * HD];
    __shared__ float sV[HD * HD];
    __shared__ float sQ[TT * HD * HD];
    __shared__ float sh[8 * HD];
    const float* wk = Wk + layer * HD * HD;
    const float* wv = Wv + layer * HD * HD;
    for (int i = threadIdx.x; i < HD * HD; i += 256) { sK[i] = wk[i]; sV[i] = wv[i]; }
    for (int i = threadIdx.x; i < TT * HD * HD; i += 256) sQ[i] = WqR[i];
    int node0 = blockIdx.x * 8;
    {
        const float4* hs = (const float4*)(h + (size_t)node0 * HD);
        float4* dst4 = (float4*)sh;
        if (threadIdx.x < 64) dst4[threadIdx.x] = hs[threadIdx.x];
    }
    __syncthreads();
    int ln = threadIdx.x / HD, d = threadIdx.x % HD;
    int n = node0 + ln;
    float ak = 0.f, av = 0.f, a0 = 0.f, a1 = 0.f, a2 = 0.f;
    #pragma unroll
    for (int i = 0; i < HD; ++i) {
        float hv = sh[ln * HD + i];
        ak += hv * sK[i * HD + d];
        av += hv * sV[i * HD + d];
        a0 += hv * sQ[0 * HD * HD + i * HD + d];
        a1 += hv * sQ[1 * HD * HD + i * HD + d];
        a2 += hv * sQ[2 * HD * HD + i * HD + d];
    }
    k[(size_t)n * HD + d] = ak;
    v[(size_t)n * HD + d] = av;
    q_rel[(0 * (size_t)NN + n) * HD + d] = a0;
    q_rel[(1 * (size_t)NN + n) * HD + d] = a1;
    q_rel[(2 * (size_t)NN + n) * HD + d] = a2;
}

// logits in CSR slot order: 8 lanes per slot, coalesced einfo/dcsr/a_csr
__global__ void edge_logits_csr(const int* __restrict__ einfo, const int* __restrict__ dcsr,
                                const float* __restrict__ k, const float* __restrict__ q_rel,
                                float* __restrict__ a_csr) {
    int p = blockIdx.x * 32 + (threadIdx.x >> 3);
    if (p >= NE) return;
    int g = threadIdx.x & 7;
    int sid = einfo[p];
    int srcn = ((unsigned)sid) >> 2, t = sid & 3;
    int dn = dcsr[p];
    float4 kv = *(const float4*)(k + (size_t)srcn * HD + 4 * g);
    float4 qv = *(const float4*)(q_rel + ((size_t)t * NN + dn) * HD + 4 * g);
    float acc = kv.x * qv.x + kv.y * qv.y + kv.z * qv.z + kv.w * qv.w;
    acc += __shfl_xor(acc, 1);
    acc += __shfl_xor(acc, 2);
    acc += __shfl_xor(acc, 4);
    if (g == 0) a_csr[p] = acc;
}

// one (dst,type)-segment aggregation: unroll-4, independent gathers
__device__ __forceinline__ float seg_agg(int s0, int s1,
                                         const float* __restrict__ a_csr,
                                         const int* __restrict__ einfo,
                                         const float* __restrict__ v,
                                         int d, float m, float& den) {
    float acc = 0.f;
    int i = s0;
    for (; i + 4 <= s1; i += 4) {
        float a0 = a_csr[i], a1 = a_csr[i + 1], a2 = a_csr[i + 2], a3 = a_csr[i + 3];
        unsigned e0 = (unsigned)einfo[i] >> 2, e1 = (unsigned)einfo[i + 1] >> 2;
        unsigned e2 = (unsigned)einfo[i + 2] >> 2, e3 = (unsigned)einfo[i + 3] >> 2;
        float v0 = v[(size_t)e0 * HD + d], v1 = v[(size_t)e1 * HD + d];
        float v2 = v[(size_t)e2 * HD + d], v3 = v[(size_t)e3 * HD + d];
        float x0 = __expf(a0 - m), x1 = __expf(a1 - m);
        float x2 = __expf(a2 - m), x3 = __expf(a3 - m);
        den += (x0 + x1) + (x2 + x3);
        acc += x0 * v0 + x1 * v1 + x2 * v2 + x3 * v3;
    }
    for (; i < s1; ++i) {
        float x = __expf(a_csr[i] - m);
        unsigned e = (unsigned)einfo[i] >> 2;
        den += x;
        acc += x * v[(size_t)e * HD + d];
    }
    return acc;
}

// per-node softmax + per-type aggregation of RAW v + (Rmsg_t@Wa) + gate + relu
__global__ void node_agg_out3(const int* __restrict__ rp, const int* __restrict__ einfo,
                              const float* __restrict__ a_csr, const float* __restrict__ v,
                              const float* __restrict__ RW, const float* __restrict__ skip,
                              float* __restrict__ h, int layer) {
    __shared__ float sRW[TT * HD * HD];   // 12 KB
    __shared__ float su[8 * TT * HD];     // 3 KB
    for (int i = threadIdx.x; i < TT * HD * HD; i += 256) sRW[i] = RW[i];
    int lane = threadIdx.x & 63;
    int d = lane & 31;
    int nloc = (threadIdx.x >> 6) * 2 + (lane >> 5);
    int n = blockIdx.x * 8 + nloc;
    int b0 = rp[TT * n], b1 = rp[TT * n + 1], b2 = rp[TT * n + 2], b3 = rp[TT * n + 3];
    // segment max over the node's full contiguous range
    float m = -__builtin_inff();
    for (int i = b0 + d; i < b3; i += 32) m = fmaxf(m, a_csr[i]);
    #pragma unroll
    for (int off = 16; off; off >>= 1) m = fmaxf(m, __shfl_xor(m, off));
    // per-type aggregation, no selects
    float den = 0.f;
    float u0 = seg_agg(b0, b1, a_csr, einfo, v, d, m, den);
    float u1 = seg_agg(b1, b2, a_csr, einfo, v, d, m, den);
    float u2 = seg_agg(b2, b3, a_csr, einfo, v, d, m, den);
    float inv = (b3 > b0) ? 1.f / den : 0.f;
    su[(nloc * TT + 0) * HD + d] = u0 * inv;
    su[(nloc * TT + 1) * HD + d] = u1 * inv;
    su[(nloc * TT + 2) * HD + d] = u2 * inv;
    __syncthreads();
    float o = 0.f;
    #pragma unroll
    for (int t = 0; t < TT; ++t)
        #pragma unroll
        for (int i = 0; i < HD; ++i)
            o += su[(nloc * TT + t) * HD + i] * sRW[(t * HD + i) * HD + d];
    float gate = 1.f / (1.f + __expf(-skip[layer]));
    size_t idx = (size_t)n * HD + d;
    float val = o * gate + h[idx] * (1.f - gate);
    h[idx] = fmaxf(val, 0.f);
}

// out = h @ mlp_W + mlp_b  (C=2)
__global__ void mlp_out(const float* __restrict__ h, const float* __restrict__ W,
                        const float* __restrict__ b, float* __restrict__ out) {
    int n = blockIdx.x * blockDim.x + threadIdx.x;
    if (n >= NN) return;
    const float4* hr = (const float4*)(h + (size_t)n * HD);
    float acc0 = b[0], acc1 = b[1];
    #pragma unroll
    for (int j = 0; j < HD / 4; ++j) {
        float4 hv = hr[j];
        acc0 += hv.x * W[(4 * j + 0) * 2 + 0] + hv.y * W[(4 * j + 1) * 2 + 0]
              + hv.z * W[(4 * j + 2) * 2 + 0] + hv.w * W[(4 * j + 3) * 2 + 0];
        acc1 += hv.x * W[(4 * j + 0) * 2 + 1] + hv.y * W[(4 * j + 1) * 2 + 1]
              + hv.z * W[(4 * j + 2) * 2 + 1] + hv.w * W[(4 * j + 3) * 2 + 1];
    }
    out[(size_t)n * 2 + 0] = acc0;
    out[(size_t)n * 2 + 1] = acc1;
}

extern "C" void kernel_launch(void* const* d_in, const int* in_sizes, int n_in,
                              void* d_out, int out_size, void* d_ws, size_t ws_size,
                              hipStream_t stream) {
    const float* x     = (const float*)d_in[0];
    const int*   src   = (const int*)d_in[1];
    const int*   dst   = (const int*)d_in[2];
    const int*   etype = (const int*)d_in[3];
    const float* in_W  = (const float*)d_in[4];
    const float* in_b  = (const float*)d_in[5];
    const float* Wk    = (const float*)d_in[6];
    const float* Wq    = (const float*)d_in[7];
    const float* Wv    = (const float*)d_in[8];
    const float* Wa    = (const float*)d_in[9];
    const float* pri   = (const float*)d_in[10];
    const float* Ratt  = (const float*)d_in[11];
    const float* Rmsg  = (const float*)d_in[12];
    const float* skip  = (const float*)d_in[13];
    const float* mlp_W = (const float*)d_in[14];
    const float* mlp_b = (const float*)d_in[15];
    float* out = (float*)d_out;

    float* ws = (float*)d_ws;
    float* h      = ws;                            // NN*HD
    float* k      = h + (size_t)NN * HD;           // NN*HD
    float* v      = k + (size_t)NN * HD;           // NN*HD
    float* q_rel  = v + (size_t)NN * HD;           // 3*NN*HD
    float* a_csr  = q_rel + (size_t)3 * NN * HD;   // NE
    float* WqR    = a_csr + NE;                    // 3*HD*HD
    float* RW     = WqR + TT * HD * HD;            // 3*HD*HD
    int* rowptr   = (int*)(RW + TT * HD * HD);     // MM+1
    int* cnt      = rowptr + MM + 1;               // MM
    int* fill     = cnt + MM;                      // MM
    int* bsum     = fill + MM;                     // 512
    int* bofs     = bsum + 512;                    // 512
    int* einfo    = bofs + 512;                    // NE
    int* dcsr     = einfo + NE;                    // NE

    input_proj<<<NN / 8, 256, 0, stream>>>(x, in_W, in_b, h);

    init_csr<<<(MM + 255) / 256, 256, 0, stream>>>(cnt, fill);
    count_dst_part<<<8 * PSLICE, 256, 0, stream>>>(dst, etype, cnt);
    scan1<<<NBLK2, 1024, 0, stream>>>(cnt, rowptr, bsum);
    scan2<<<1, 512, 0, stream>>>(bsum, bofs);
    scan3<<<NBLK2, 1024, 0, stream>>>(rowptr, bofs);
    scatter_part<<<8 * PSLICE, 256, 0, stream>>>(src, dst, etype, rowptr, fill, einfo);
    fill_dcsr<<<NBLK, 256, 0, stream>>>(rowptr, dcsr);

    for (int l = 0; l < LL; ++l) {
        combine_mats2<<<(2 * TT * HD * HD + 255) / 256, 256, 0, stream>>>(
            Wq, Ratt, Rmsg, Wa, pri, WqR, RW, l);
        node_proj5<<<NN / 8, 256, 0, stream>>>(h, Wk, Wv, WqR, k, v, q_rel, l);
        edge_logits_csr<<<(NE + 31) / 32, 256, 0, stream>>>(einfo, dcsr, k, q_rel, a_csr);
        node_agg_out3<<<NN / 8, 256, 0, stream>>>(rowptr, einfo, a_csr, v, RW, skip, h, l);
    }
    mlp_out<<<(NN + 255) / 256, 256, 0, stream>>>(h, mlp_W, mlp_b, out);
}

// Round 5
// 455.449 us; speedup vs baseline: 12.8644x; 1.2317x over previous
//
#include <hip/hip_runtime.h>

#define NN   100000     // nodes
#define NE   1600000    // edges
#define INF_ 128        // input features
#define HD   32         // hidden = HEADS*HEAD_D
#define TT   3          // edge types
#define LL   2          // layers
#define NBLK ((NN + 255) / 256)

// binning sort parameters
#define BSH   9                      // 512 nodes per bucket
#define NBUK  ((NN + 511) / 512)     // 196 buckets
#define BCAP  12288                  // slots per bucket (mean 8163, huge margin)
#define CHUNK 4096                   // edges per bin_edges block
#define EPT   16                     // edges per thread
#define NCHNK ((NE + CHUNK - 1) / CHUNK)  // 391
#define NSEG  (512 * TT)             // 1536 segments per bucket

static const float RSQRT_D = 0.17677669529663687f;  // 1/sqrt(32)

// h = x @ in_W + in_b   (block: 8 nodes x 32 dims)
__global__ void input_proj(const float* __restrict__ x,
                           const float* __restrict__ inW,
                           const float* __restrict__ inb,
                           float* __restrict__ h) {
    __shared__ float sW[INF_ * HD];   // 16 KB
    __shared__ float sx[8 * INF_];    // 4 KB
    for (int i = threadIdx.x; i < INF_ * HD; i += 256) sW[i] = inW[i];
    int node0 = blockIdx.x * 8;
    {
        const float4* xs = (const float4*)(x + (size_t)node0 * INF_);
        float4* dst4 = (float4*)sx;
        dst4[threadIdx.x] = xs[threadIdx.x];
    }
    __syncthreads();
    int ln = threadIdx.x / HD, d = threadIdx.x % HD;
    int n = node0 + ln;
    float acc = inb[d];
    #pragma unroll
    for (int i = 0; i < INF_; ++i) acc += sx[ln * INF_ + i] * sW[i * HD + d];
    h[(size_t)n * HD + d] = acc;
}

// ---------------- CSR build: LDS-staged two-pass binning ----------------
__global__ void zero_cursor(int* __restrict__ cursor) {
    if (threadIdx.x < NBUK) cursor[threadIdx.x] = 0;
}

// pass A: bin edges by dst>>9; chunk-local LDS reorder, near-coalesced writes
__global__ void bin_edges(const int* __restrict__ src, const int* __restrict__ dst,
                          const int* __restrict__ etype,
                          unsigned* __restrict__ bin, int* __restrict__ cursor) {
    __shared__ int hist[256];            // per-bucket count -> exclusive prefix
    __shared__ int scn[256];             // inclusive scan
    __shared__ int gofs[256];            // global base per bucket
    __shared__ int fillc[256];           // local fill counters
    __shared__ unsigned buf[CHUNK];      // 16 KB reordered entries
    __shared__ unsigned short bufb[CHUNK]; // 8 KB bucket id per slot
    int tid = threadIdx.x;
    int e0 = blockIdx.x * CHUNK;
    unsigned ent[EPT];
    int bkt[EPT];
    hist[tid] = 0;
    fillc[tid] = 0;
    __syncthreads();
    #pragma unroll
    for (int j = 0; j < EPT; ++j) {
        int e = e0 + j * 256 + tid;
        if (e < NE) {
            int dn = dst[e];
            int b = dn >> BSH;
            ent[j] = ((unsigned)src[e] << 11) | ((unsigned)(dn & 511) << 2)
                   | (unsigned)etype[e];
            bkt[j] = b;
            atomicAdd(&hist[b], 1);
        } else bkt[j] = -1;
    }
    __syncthreads();
    int v = hist[tid];
    scn[tid] = v;
    __syncthreads();
    for (int off = 1; off < 256; off <<= 1) {
        int t = (tid >= off) ? scn[tid - off] : 0;
        __syncthreads();
        scn[tid] += t;
        __syncthreads();
    }
    int excl = scn[tid] - v;
    int total = scn[255];
    if (v > 0) gofs[tid] = atomicAdd(&cursor[tid], v);
    hist[tid] = excl;   // hist now holds chunk-local exclusive prefix
    __syncthreads();
    #pragma unroll
    for (int j = 0; j < EPT; ++j) {
        if (bkt[j] >= 0) {
            int r = atomicAdd(&fillc[bkt[j]], 1);
            int pos = hist[bkt[j]] + r;
            buf[pos] = ent[j];
            bufb[pos] = (unsigned short)bkt[j];
        }
    }
    __syncthreads();
    for (int pos = tid; pos < total; pos += 256) {
        int b = bufb[pos];
        int g = gofs[b] + (pos - hist[b]);
        bin[(size_t)b * BCAP + g] = buf[pos];
    }
}

// exclusive scan over NBUK bucket totals
__global__ void scan_buckets(const int* __restrict__ cursor, int* __restrict__ bbase) {
    __shared__ int s[256];
    int tid = threadIdx.x;
    int v = (tid < NBUK) ? cursor[tid] : 0;
    s[tid] = v;
    __syncthreads();
    for (int off = 1; off < 256; off <<= 1) {
        int t = (tid >= off) ? s[tid - off] : 0;
        __syncthreads();
        s[tid] += t;
        __syncthreads();
    }
    if (tid < NBUK) bbase[tid] = s[tid] - v;
}

// pass B: per-bucket segment hist + scan + rowptr + placement (einfo, dcsr)
__global__ void build_bucket(const unsigned* __restrict__ bin, const int* __restrict__ cursor,
                             const int* __restrict__ bbase, int* __restrict__ rowptr,
                             int* __restrict__ einfo, int* __restrict__ dcsr) {
    __shared__ int hist[NSEG];    // 6 KB
    __shared__ int fill2[NSEG];   // 6 KB
    __shared__ int tsum[256];
    int b = blockIdx.x, tid = threadIdx.x;
    int cnt = cursor[b], base = bbase[b];
    const unsigned* eb = bin + (size_t)b * BCAP;
    for (int j = tid; j < NSEG; j += 256) { hist[j] = 0; fill2[j] = 0; }
    __syncthreads();
    for (int i = tid; i < cnt; i += 256) {
        unsigned u = eb[i];
        atomicAdd(&hist[((u >> 2) & 511) * TT + (u & 3)], 1);
    }
    __syncthreads();
    int b6 = tid * 6;
    int s = 0;
    #pragma unroll
    for (int j = 0; j < 6; ++j) s += hist[b6 + j];
    tsum[tid] = s;
    __syncthreads();
    for (int off = 1; off < 256; off <<= 1) {
        int t = (tid >= off) ? tsum[tid - off] : 0;
        __syncthreads();
        tsum[tid] += t;
        __syncthreads();
    }
    int run = tsum[tid] - s;
    #pragma unroll
    for (int j = 0; j < 6; ++j) { int c = hist[b6 + j]; hist[b6 + j] = run; run += c; }
    __syncthreads();
    for (int j = tid; j < NSEG; j += 256) rowptr[b * NSEG + j] = base + hist[j];
    for (int i = tid; i < cnt; i += 256) {
        unsigned u = eb[i];
        int t = u & 3, dl = (u >> 2) & 511, sn = u >> 11;
        int seg = dl * TT + t;
        int p = base + hist[seg] + atomicAdd(&fill2[seg], 1);
        einfo[p] = (sn << 2) | t;
        dcsr[p] = (b << BSH) + dl;
    }
}

// ---------------- per-layer kernels ----------------

// WqR[t] = Wq_l @ Ratt_t^T * pri_t / sqrt(d);  RW[t] = Rmsg_t @ Wa_l
__global__ void combine_mats2(const float* __restrict__ Wq, const float* __restrict__ Ratt,
                              const float* __restrict__ Rmsg, const float* __restrict__ Wa,
                              const float* __restrict__ pri,
                              float* __restrict__ WqR, float* __restrict__ RW, int layer) {
    int idx = blockIdx.x * blockDim.x + threadIdx.x;   // 6144
    if (idx >= 2 * TT * HD * HD) return;
    int which = idx / (TT * HD * HD);
    int rr = idx % (TT * HD * HD);
    int t = rr / (HD * HD);
    int ij = rr % (HD * HD);
    int i = ij / HD, j = ij % HD;
    if (which == 0) {
        const float* wq = Wq + layer * HD * HD;
        const float* ra = Ratt + (size_t)(layer * TT + t) * HD * HD;
        float acc = 0.f;
        #pragma unroll
        for (int e = 0; e < HD; ++e) acc += wq[i * HD + e] * ra[j * HD + e];
        WqR[t * HD * HD + ij] = acc * pri[layer * TT + t] * RSQRT_D;
    } else {
        const float* rm = Rmsg + (size_t)(layer * TT + t) * HD * HD;
        const float* wa = Wa + layer * HD * HD;
        float acc = 0.f;
        #pragma unroll
        for (int e = 0; e < HD; ++e) acc += rm[i * HD + e] * wa[e * HD + j];
        RW[t * HD * HD + ij] = acc;
    }
}

// per node: k = h@Wk ; v = h@Wv ; q_rel[t] = h@WqR[t]
__global__ void node_proj5(const float* __restrict__ h, const float* __restrict__ Wk,
                           const float* __restrict__ Wv, const float* __restrict__ WqR,
                           float* __restrict__ k, float* __restrict__ v,
                           float* __restrict__ q_rel, int layer) {
    __shared__ float sK[HD * HD];
    __shared__ float sV[HD * HD];
    __shared__ float sQ[TT * HD * HD];
    __shared__ float sh[8 * HD];
    const float* wk = Wk + layer * HD * HD;
    const float* wv = Wv + layer * HD * HD;
    for (int i = threadIdx.x; i < HD * HD; i += 256) { sK[i] = wk[i]; sV[i] = wv[i]; }
    for (int i = threadIdx.x; i < TT * HD * HD; i += 256) sQ[i] = WqR[i];
    int node0 = blockIdx.x * 8;
    {
        const float4* hs = (const float4*)(h + (size_t)node0 * HD);
        float4* dst4 = (float4*)sh;
        if (threadIdx.x < 64) dst4[threadIdx.x] = hs[threadIdx.x];
    }
    __syncthreads();
    int ln = threadIdx.x / HD, d = threadIdx.x % HD;
    int n = node0 + ln;
    float ak = 0.f, av = 0.f, a0 = 0.f, a1 = 0.f, a2 = 0.f;
    #pragma unroll
    for (int i = 0; i < HD; ++i) {
        float hv = sh[ln * HD + i];
        ak += hv * sK[i * HD + d];
        av += hv * sV[i * HD + d];
        a0 += hv * sQ[0 * HD * HD + i * HD + d];
        a1 += hv * sQ[1 * HD * HD + i * HD + d];
        a2 += hv * sQ[2 * HD * HD + i * HD + d];
    }
    k[(size_t)n * HD + d] = ak;
    v[(size_t)n * HD + d] = av;
    q_rel[(0 * (size_t)NN + n) * HD + d] = a0;
    q_rel[(1 * (size_t)NN + n) * HD + d] = a1;
    q_rel[(2 * (size_t)NN + n) * HD + d] = a2;
}

// logits in CSR slot order: 8 lanes per slot, coalesced einfo/dcsr/a_csr
__global__ void edge_logits_csr(const int* __restrict__ einfo, const int* __restrict__ dcsr,
                                const float* __restrict__ k, const float* __restrict__ q_rel,
                                float* __restrict__ a_csr) {
    int p = blockIdx.x * 32 + (threadIdx.x >> 3);
    if (p >= NE) return;
    int g = threadIdx.x & 7;
    int sid = einfo[p];
    int srcn = ((unsigned)sid) >> 2, t = sid & 3;
    int dn = dcsr[p];
    float4 kv = *(const float4*)(k + (size_t)srcn * HD + 4 * g);
    float4 qv = *(const float4*)(q_rel + ((size_t)t * NN + dn) * HD + 4 * g);
    float acc = kv.x * qv.x + kv.y * qv.y + kv.z * qv.z + kv.w * qv.w;
    acc += __shfl_xor(acc, 1);
    acc += __shfl_xor(acc, 2);
    acc += __shfl_xor(acc, 4);
    if (g == 0) a_csr[p] = acc;
}

// one (dst,type)-segment aggregation: unroll-4, independent gathers
__device__ __forceinline__ float seg_agg(int s0, int s1,
                                         const float* __restrict__ a_csr,
                                         const int* __restrict__ einfo,
                                         const float* __restrict__ v,
                                         int d, float m, float& den) {
    float acc = 0.f;
    int i = s0;
    for (; i + 4 <= s1; i += 4) {
        float a0 = a_csr[i], a1 = a_csr[i + 1], a2 = a_csr[i + 2], a3 = a_csr[i + 3];
        unsigned e0 = (unsigned)einfo[i] >> 2, e1 = (unsigned)einfo[i + 1] >> 2;
        unsigned e2 = (unsigned)einfo[i + 2] >> 2, e3 = (unsigned)einfo[i + 3] >> 2;
        float v0 = v[(size_t)e0 * HD + d], v1 = v[(size_t)e1 * HD + d];
        float v2 = v[(size_t)e2 * HD + d], v3 = v[(size_t)e3 * HD + d];
        float x0 = __expf(a0 - m), x1 = __expf(a1 - m);
        float x2 = __expf(a2 - m), x3 = __expf(a3 - m);
        den += (x0 + x1) + (x2 + x3);
        acc += x0 * v0 + x1 * v1 + x2 * v2 + x3 * v3;
    }
    for (; i < s1; ++i) {
        float x = __expf(a_csr[i] - m);
        unsigned e = (unsigned)einfo[i] >> 2;
        den += x;
        acc += x * v[(size_t)e * HD + d];
    }
    return acc;
}

// per-node softmax + per-type aggregation of RAW v + (Rmsg_t@Wa) + gate + relu
__global__ void node_agg_out3(const int* __restrict__ rp, const int* __restrict__ einfo,
                              const float* __restrict__ a_csr, const float* __restrict__ v,
                              const float* __restrict__ RW, const float* __restrict__ skip,
                              float* __restrict__ h, int layer) {
    __shared__ float sRW[TT * HD * HD];   // 12 KB
    __shared__ float su[8 * TT * HD];     // 3 KB
    for (int i = threadIdx.x; i < TT * HD * HD; i += 256) sRW[i] = RW[i];
    int lane = threadIdx.x & 63;
    int d = lane & 31;
    int nloc = (threadIdx.x >> 6) * 2 + (lane >> 5);
    int n = blockIdx.x * 8 + nloc;
    int b0 = rp[TT * n], b1 = rp[TT * n + 1], b2 = rp[TT * n + 2], b3 = rp[TT * n + 3];
    float m = -__builtin_inff();
    for (int i = b0 + d; i < b3; i += 32) m = fmaxf(m, a_csr[i]);
    #pragma unroll
    for (int off = 16; off; off >>= 1) m = fmaxf(m, __shfl_xor(m, off));
    float den = 0.f;
    float u0 = seg_agg(b0, b1, a_csr, einfo, v, d, m, den);
    float u1 = seg_agg(b1, b2, a_csr, einfo, v, d, m, den);
    float u2 = seg_agg(b2, b3, a_csr, einfo, v, d, m, den);
    float inv = (b3 > b0) ? 1.f / den : 0.f;
    su[(nloc * TT + 0) * HD + d] = u0 * inv;
    su[(nloc * TT + 1) * HD + d] = u1 * inv;
    su[(nloc * TT + 2) * HD + d] = u2 * inv;
    __syncthreads();
    float o = 0.f;
    #pragma unroll
    for (int t = 0; t < TT; ++t)
        #pragma unroll
        for (int i = 0; i < HD; ++i)
            o += su[(nloc * TT + t) * HD + i] * sRW[(t * HD + i) * HD + d];
    float gate = 1.f / (1.f + __expf(-skip[layer]));
    size_t idx = (size_t)n * HD + d;
    float val = o * gate + h[idx] * (1.f - gate);
    h[idx] = fmaxf(val, 0.f);
}

// out = h @ mlp_W + mlp_b  (C=2)
__global__ void mlp_out(const float* __restrict__ h, const float* __restrict__ W,
                        const float* __restrict__ b, float* __restrict__ out) {
    int n = blockIdx.x * blockDim.x + threadIdx.x;
    if (n >= NN) return;
    const float4* hr = (const float4*)(h + (size_t)n * HD);
    float acc0 = b[0], acc1 = b[1];
    #pragma unroll
    for (int j = 0; j < HD / 4; ++j) {
        float4 hv = hr[j];
        acc0 += hv.x * W[(4 * j + 0) * 2 + 0] + hv.y * W[(4 * j + 1) * 2 + 0]
              + hv.z * W[(4 * j + 2) * 2 + 0] + hv.w * W[(4 * j + 3) * 2 + 0];
        acc1 += hv.x * W[(4 * j + 0) * 2 + 1] + hv.y * W[(4 * j + 1) * 2 + 1]
              + hv.z * W[(4 * j + 2) * 2 + 1] + hv.w * W[(4 * j + 3) * 2 + 1];
    }
    out[(size_t)n * 2 + 0] = acc0;
    out[(size_t)n * 2 + 1] = acc1;
}

extern "C" void kernel_launch(void* const* d_in, const int* in_sizes, int n_in,
                              void* d_out, int out_size, void* d_ws, size_t ws_size,
                              hipStream_t stream) {
    const float* x     = (const float*)d_in[0];
    const int*   src   = (const int*)d_in[1];
    const int*   dst   = (const int*)d_in[2];
    const int*   etype = (const int*)d_in[3];
    const float* in_W  = (const float*)d_in[4];
    const float* in_b  = (const float*)d_in[5];
    const float* Wk    = (const float*)d_in[6];
    const float* Wq    = (const float*)d_in[7];
    const float* Wv    = (const float*)d_in[8];
    const float* Wa    = (const float*)d_in[9];
    const float* pri   = (const float*)d_in[10];
    const float* Ratt  = (const float*)d_in[11];
    const float* Rmsg  = (const float*)d_in[12];
    const float* skip  = (const float*)d_in[13];
    const float* mlp_W = (const float*)d_in[14];
    const float* mlp_b = (const float*)d_in[15];
    float* out = (float*)d_out;

    float* ws = (float*)d_ws;
    float* h      = ws;                            // NN*HD
    float* k      = h + (size_t)NN * HD;           // NN*HD
    float* v      = k + (size_t)NN * HD;           // NN*HD
    float* q_rel  = v + (size_t)NN * HD;           // 3*NN*HD
    float* a_csr  = q_rel + (size_t)3 * NN * HD;   // NE
    float* WqR    = a_csr + NE;                    // 3*HD*HD
    float* RW     = WqR + TT * HD * HD;            // 3*HD*HD
    int* rowptr   = (int*)(RW + TT * HD * HD);     // NBUK*NSEG + 1
    int* cursor   = rowptr + NBUK * NSEG + 1;      // 256
    int* bbase    = cursor + 256;                  // 256
    int* einfo    = bbase + 256;                   // NE
    int* dcsr     = einfo + NE;                    // NE
    unsigned* bin = (unsigned*)(dcsr + NE);        // NBUK*BCAP

    input_proj<<<NN / 8, 256, 0, stream>>>(x, in_W, in_b, h);

    zero_cursor<<<1, 256, 0, stream>>>(cursor);
    bin_edges<<<NCHNK, 256, 0, stream>>>(src, dst, etype, bin, cursor);
    scan_buckets<<<1, 256, 0, stream>>>(cursor, bbase);
    build_bucket<<<NBUK, 256, 0, stream>>>(bin, cursor, bbase, rowptr, einfo, dcsr);

    for (int l = 0; l < LL; ++l) {
        combine_mats2<<<(2 * TT * HD * HD + 255) / 256, 256, 0, stream>>>(
            Wq, Ratt, Rmsg, Wa, pri, WqR, RW, l);
        node_proj5<<<NN / 8, 256, 0, stream>>>(h, Wk, Wv, WqR, k, v, q_rel, l);
        edge_logits_csr<<<(NE + 31) / 32, 256, 0, stream>>>(einfo, dcsr, k, q_rel, a_csr);
        node_agg_out3<<<NN / 8, 256, 0, stream>>>(rowptr, einfo, a_csr, v, RW, skip, h, l);
    }
    mlp_out<<<(NN + 255) / 256, 256, 0, stream>>>(h, mlp_W, mlp_b, out);
}